// Round 1
// baseline (15472.255 us; speedup 1.0000x reference)
//
#include <hip/hip_runtime.h>
#include <hip/hip_bf16.h>
#include <hip/hip_cooperative_groups.h>

namespace cg = cooperative_groups;

typedef __attribute__((ext_vector_type(8))) short bf16x8;
typedef __attribute__((ext_vector_type(4))) float f32x4;

#define T_STEPS 256
#define BATCH   64
#define KDIM    1024
#define HDIM    1024
#define NGATE   3072   // 3*HDIM
#define LAYERS  3

// ---------- helpers ----------
__device__ __forceinline__ unsigned short f2b(float f) {
  union { float f; unsigned int u; } a; a.f = f;
  unsigned int u = a.u;
  unsigned int r = (u + 0x7FFFu + ((u >> 16) & 1u)) >> 16;  // RNE
  return (unsigned short)r;
}
__device__ __forceinline__ float b2f(unsigned short h) {
  union { unsigned int u; float f; } a; a.u = ((unsigned int)h) << 16;
  return a.f;
}
// async global->LDS, 16B per lane. LDS dest semantics: wave-uniform base + lane*16.
__device__ __forceinline__ void gload16(const void* gptr, void* ldsptr) {
  __builtin_amdgcn_global_load_lds(
      (const __attribute__((address_space(1))) unsigned int*)gptr,
      (__attribute__((address_space(3))) unsigned int*)ldsptr,
      16, 0, 0);
}

// ---------- fp32 -> bf16 bulk convert (4 elems/thread) ----------
__global__ void f2b_kernel(const float* __restrict__ src,
                           unsigned short* __restrict__ dst, int n4) {
  int i = blockIdx.x * blockDim.x + threadIdx.x;
  if (i < n4) {
    float4 v = ((const float4*)src)[i];
    ushort4 o;
    o.x = f2b(v.x); o.y = f2b(v.y); o.z = f2b(v.z); o.w = f2b(v.w);
    ((ushort4*)dst)[i] = o;
  }
}

// ---------- swizzle whh into MFMA B-fragment-major layout ----------
// out layout: [l][ntile(192)][kc(32)][lane(64)][8 bf16]; one thread = one 8-elem group
__global__ void swizzle_whh(const float* __restrict__ whh,
                            unsigned short* __restrict__ out) {
  long gid = (long)blockIdx.x * 256 + threadIdx.x;   // < 3*192*32*64
  int lane = (int)(gid & 63);
  long rest = gid >> 6;
  int kc = (int)(rest & 31); rest >>= 5;
  int ntile = (int)(rest % 192); int l = (int)(rest / 192);
  int n  = ntile * 16 + (lane & 15);
  int k0 = kc * 32 + (lane >> 4) * 8;
  const float* src = whh + (((long)l * NGATE + n) * KDIM + k0);
  unsigned short o[8];
#pragma unroll
  for (int j = 0; j < 8; j++) o[j] = f2b(src[j]);
  bf16x8 v = *(bf16x8*)o;
  *(bf16x8*)(out + gid * 8) = v;
}

// ---------- gi GEMM: C[M,N] = A[M,K] * B[N,K]^T + bias, bf16 in/out, fp32 acc ----------
#define BM 128
#define BN 128
#define BK 32
__global__ __launch_bounds__(256) void gemm_gi(
    const unsigned short* __restrict__ A,   // [M][K] bf16
    const unsigned short* __restrict__ B,   // [N][K] bf16
    const float* __restrict__ bias,         // [N]
    unsigned short* __restrict__ C,         // [M][N] bf16
    int M, int N, int K) {
  __shared__ alignas(16) unsigned short As[BM * BK];
  __shared__ alignas(16) unsigned short Bs[BN * BK];
  int tid = threadIdx.x;
  int wave = tid >> 6, lane = tid & 63;
  int m0 = blockIdx.x * BM, n0 = blockIdx.y * BN;
  int wr = (wave >> 1) * 64, wc = (wave & 1) * 64;

  f32x4 acc[4][4] = {};

  const unsigned short* Ab = A + (long)m0 * K;
  const unsigned short* Bb = B + (long)n0 * K;
  int r0 = tid >> 2, g0 = (tid & 3) * 8;      // staging: row, k-offset (elems)

  for (int k0 = 0; k0 < K; k0 += BK) {
    gload16(Ab + (long)r0 * K + k0 + g0,        &As[(size_t)tid * 8]);
    gload16(Ab + (long)(r0 + 64) * K + k0 + g0, &As[(size_t)(256 + tid) * 8]);
    gload16(Bb + (long)r0 * K + k0 + g0,        &Bs[(size_t)tid * 8]);
    gload16(Bb + (long)(r0 + 64) * K + k0 + g0, &Bs[(size_t)(256 + tid) * 8]);
    __syncthreads();
    bf16x8 af[4], bf[4];
#pragma unroll
    for (int i = 0; i < 4; i++)
      af[i] = *(const bf16x8*)&As[(wr + i * 16 + (lane & 15)) * BK + (lane >> 4) * 8];
#pragma unroll
    for (int j = 0; j < 4; j++)
      bf[j] = *(const bf16x8*)&Bs[(wc + j * 16 + (lane & 15)) * BK + (lane >> 4) * 8];
#pragma unroll
    for (int i = 0; i < 4; i++)
#pragma unroll
      for (int j = 0; j < 4; j++)
        acc[i][j] = __builtin_amdgcn_mfma_f32_16x16x32_bf16(af[i], bf[j], acc[i][j], 0, 0, 0);
    __syncthreads();
  }

#pragma unroll
  for (int j = 0; j < 4; j++) {
    int col = n0 + wc + j * 16 + (lane & 15);
    float bv = bias[col];
#pragma unroll
    for (int i = 0; i < 4; i++) {
      int rbase = m0 + wr + i * 16 + ((lane >> 4) << 2);
      f32x4 v = acc[i][j];
#pragma unroll
      for (int r = 0; r < 4; r++)
        C[(long)(rbase + r) * N + col] = f2b(v[r] + bv);
    }
  }
}

// ---------- persistent GRU recurrence, one layer ----------
// grid: 64 wgs x 256 thr (cooperative). wg g owns output cols [16g,16g+16) for all 3 gates.
__global__ __launch_bounds__(256) void gru_recur(
    const unsigned short* __restrict__ gi,    // [T*B][3072] bf16 (includes b_ih)
    const unsigned short* __restrict__ wsw,   // swizzled whh: [ntile192][kc32][64][8]
    const float* __restrict__ bhh,            // [3072]
    const float* __restrict__ h0,             // [64][1024] fp32
    unsigned short* __restrict__ hbuf,        // [2][64][1024] bf16 (double buffer)
    unsigned short* __restrict__ outseq,      // [T*B][1024] bf16 (layer output)
    float* __restrict__ hout)                 // [64][1024] fp32 -> d_out slice
{
  cg::grid_group grid = cg::this_grid();
  __shared__ alignas(16) unsigned short As[64 * 64];   // h tile [row64][k64]
  int tid = threadIdx.x, wave = tid >> 6, lane = tid & 63;
  int g = blockIdx.x;
  int colc = g * 16 + (lane & 15);               // this lane's H-column
  int rowb = wave * 16 + ((lane >> 4) << 2);     // base batch row for 4 acc regs

  // init fp32 h state in registers; publish bf16 h to buffer 0
  float h[4];
#pragma unroll
  for (int r = 0; r < 4; r++) {
    h[r] = h0[(rowb + r) * HDIM + colc];
    hbuf[(rowb + r) * HDIM + colc] = f2b(h[r]);
  }
  float bh_r = bhh[0 * HDIM + colc];
  float bh_z = bhh[1 * HDIM + colc];
  float bh_n = bhh[2 * HDIM + colc];
  grid.sync();

  int s_r0 = tid >> 3, s_g0 = (tid & 7) * 8;     // staging indices for As
  int cur = 0;
  for (int t = 0; t < T_STEPS; t++) {
    const unsigned short* hb = hbuf + (size_t)cur * (BATCH * HDIM);
    f32x4 acc[3] = {};
#pragma unroll 1
    for (int kb = 0; kb < 16; kb++) {            // K blocks of 64
      gload16(hb + (long)s_r0 * HDIM + kb * 64 + s_g0,        &As[(size_t)tid * 8]);
      gload16(hb + (long)(s_r0 + 32) * HDIM + kb * 64 + s_g0, &As[(size_t)(256 + tid) * 8]);
      __syncthreads();
#pragma unroll
      for (int ks = 0; ks < 2; ks++) {
        int kc = kb * 2 + ks;
        bf16x8 af = *(const bf16x8*)&As[(wave * 16 + (lane & 15)) * 64 + ks * 32 + (lane >> 4) * 8];
#pragma unroll
        for (int gate = 0; gate < 3; gate++) {
          int ntile = gate * 64 + g;
          bf16x8 bfr = *(const bf16x8*)(wsw + (((long)ntile * 32 + kc) * 64 + lane) * 8);
          acc[gate] = __builtin_amdgcn_mfma_f32_16x16x32_bf16(af, bfr, acc[gate], 0, 0, 0);
        }
      }
      __syncthreads();
    }
    // gates + state update (C/D: col=lane&15, row=(lane>>4)*4+reg)
    const unsigned short* gib = gi + (long)t * BATCH * NGATE;
    unsigned short* ob = outseq + (long)t * BATCH * HDIM;
    unsigned short* hn = hbuf + (size_t)(cur ^ 1) * (BATCH * HDIM);
#pragma unroll
    for (int r = 0; r < 4; r++) {
      long grow = (long)(rowb + r) * NGATE;
      float gr = b2f(gib[grow + 0 * HDIM + colc]);
      float gz = b2f(gib[grow + 1 * HDIM + colc]);
      float gn = b2f(gib[grow + 2 * HDIM + colc]);
      float xr = gr + acc[0][r] + bh_r;
      float xz = gz + acc[1][r] + bh_z;
      float rr = 1.0f / (1.0f + __expf(-xr));
      float zz = 1.0f / (1.0f + __expf(-xz));
      float nn = tanhf(gn + rr * (acc[2][r] + bh_n));
      float hv = (1.0f - zz) * nn + zz * h[r];
      h[r] = hv;
      unsigned short hb16 = f2b(hv);
      ob[(rowb + r) * HDIM + colc] = hb16;
      hn[(rowb + r) * HDIM + colc] = hb16;
      if (t == T_STEPS - 1) hout[(rowb + r) * HDIM + colc] = hv;
    }
    cur ^= 1;
    grid.sync();
  }
}

// ---------- host ----------
extern "C" void kernel_launch(void* const* d_in, const int* in_sizes, int n_in,
                              void* d_out, int out_size, void* d_ws, size_t ws_size,
                              hipStream_t stream) {
  const float* x   = (const float*)d_in[0];
  const float* h0  = (const float*)d_in[1];
  const float* wih = (const float*)d_in[2];
  const float* whh = (const float*)d_in[3];
  const float* bih = (const float*)d_in[4];
  const float* bhh = (const float*)d_in[5];
  float* out = (float*)d_out;

  char* ws = (char*)d_ws;
  unsigned short* xb   = (unsigned short*)ws; ws += (size_t)16384 * 1024 * 2;
  unsigned short* yb   = (unsigned short*)ws; ws += (size_t)16384 * 1024 * 2;
  unsigned short* gib  = (unsigned short*)ws; ws += (size_t)16384 * 3072 * 2;
  unsigned short* wihb = (unsigned short*)ws; ws += (size_t)3 * 3072 * 1024 * 2;
  unsigned short* wsw  = (unsigned short*)ws; ws += (size_t)3 * 3072 * 1024 * 2;
  unsigned short* hbuf = (unsigned short*)ws; ws += (size_t)2 * 64 * 1024 * 2;

  // converts + swizzle
  f2b_kernel<<<16384, 256, 0, stream>>>(x,   xb,   16777216 / 4);
  f2b_kernel<<<dim3((9437184 / 4 + 255) / 256), 256, 0, stream>>>(wih, wihb, 9437184 / 4);
  swizzle_whh<<<4608, 256, 0, stream>>>(whh, wsw);

  unsigned short* seq_in = xb;
  unsigned short* seq_out = yb;
  for (int l = 0; l < LAYERS; l++) {
    gemm_gi<<<dim3(16384 / BM, 3072 / BN), 256, 0, stream>>>(
        seq_in, wihb + (size_t)l * NGATE * KDIM, bih + l * NGATE, gib,
        16384, NGATE, KDIM);

    const unsigned short* a_gi  = gib;
    const unsigned short* a_wsw = wsw + (size_t)l * NGATE * KDIM;
    const float* a_bhh = bhh + l * NGATE;
    const float* a_h0  = h0 + (size_t)l * BATCH * HDIM;
    unsigned short* a_hbuf = hbuf;
    unsigned short* a_out  = seq_out;
    float* a_hout = out + (size_t)l * BATCH * HDIM;
    void* args[] = {&a_gi, &a_wsw, &a_bhh, &a_h0, &a_hbuf, &a_out, &a_hout};
    hipLaunchCooperativeKernel((void*)gru_recur, dim3(64), dim3(256), args, 0, stream);

    unsigned short* tmp = seq_in; seq_in = seq_out; seq_out = tmp;
  }
}

// Round 2
// 11951.145 us; speedup vs baseline: 1.2946x; 1.2946x over previous
//
#include <hip/hip_runtime.h>
#include <hip/hip_bf16.h>
#include <hip/hip_cooperative_groups.h>

namespace cg = cooperative_groups;

typedef __attribute__((ext_vector_type(8))) short bf16x8;
typedef __attribute__((ext_vector_type(4))) float f32x4;

#define T_STEPS 256
#define BATCH   64
#define KDIM    1024
#define HDIM    1024
#define NGATE   3072   // 3*HDIM
#define LAYERS  3

// ---------- helpers ----------
__device__ __forceinline__ unsigned short f2b(float f) {
  union { float f; unsigned int u; } a; a.f = f;
  unsigned int u = a.u;
  unsigned int r = (u + 0x7FFFu + ((u >> 16) & 1u)) >> 16;  // RNE
  return (unsigned short)r;
}
__device__ __forceinline__ float b2f(unsigned short h) {
  union { unsigned int u; float f; } a; a.u = ((unsigned int)h) << 16;
  return a.f;
}
// async global->LDS, 16B per lane. LDS dest semantics: wave-uniform base + lane*16.
__device__ __forceinline__ void gload16(const void* gptr, void* ldsptr) {
  __builtin_amdgcn_global_load_lds(
      (const __attribute__((address_space(1))) unsigned int*)gptr,
      (__attribute__((address_space(3))) unsigned int*)ldsptr,
      16, 0, 0);
}

// ---------- fp32 -> bf16 bulk convert (4 elems/thread) ----------
__global__ void f2b_kernel(const float* __restrict__ src,
                           unsigned short* __restrict__ dst, int n4) {
  int i = blockIdx.x * blockDim.x + threadIdx.x;
  if (i < n4) {
    float4 v = ((const float4*)src)[i];
    ushort4 o;
    o.x = f2b(v.x); o.y = f2b(v.y); o.z = f2b(v.z); o.w = f2b(v.w);
    ((ushort4*)dst)[i] = o;
  }
}

// ---------- swizzle whh into MFMA B-fragment-major layout ----------
// out layout: [l][ntile(192)][kc(32)][lane(64)][8 bf16]
__global__ void swizzle_whh(const float* __restrict__ whh,
                            unsigned short* __restrict__ out) {
  long gid = (long)blockIdx.x * 256 + threadIdx.x;   // < 3*192*32*64
  int lane = (int)(gid & 63);
  long rest = gid >> 6;
  int kc = (int)(rest & 31); rest >>= 5;
  int ntile = (int)(rest % 192); int l = (int)(rest / 192);
  int n  = ntile * 16 + (lane & 15);
  int k0 = kc * 32 + (lane >> 4) * 8;
  const float* src = whh + (((long)l * NGATE + n) * KDIM + k0);
  unsigned short o[8];
#pragma unroll
  for (int j = 0; j < 8; j++) o[j] = f2b(src[j]);
  bf16x8 v = *(bf16x8*)o;
  *(bf16x8*)(out + gid * 8) = v;
}

// ---------- gi GEMM: C[M,N] = A[M,K] * B[N,K]^T + bias ----------
#define BM 128
#define BN 128
#define BK 32
__global__ __launch_bounds__(256) void gemm_gi(
    const unsigned short* __restrict__ A,   // [M][K] bf16
    const unsigned short* __restrict__ B,   // [N][K] bf16
    const float* __restrict__ bias,         // [N]
    unsigned short* __restrict__ C,         // [M][N] bf16
    int M, int N, int K) {
  __shared__ alignas(16) unsigned short As[BM * BK];
  __shared__ alignas(16) unsigned short Bs[BN * BK];
  int tid = threadIdx.x;
  int wave = tid >> 6, lane = tid & 63;
  int m0 = blockIdx.x * BM, n0 = blockIdx.y * BN;
  int wr = (wave >> 1) * 64, wc = (wave & 1) * 64;

  f32x4 acc[4][4] = {};

  const unsigned short* Ab = A + (long)m0 * K;
  const unsigned short* Bb = B + (long)n0 * K;
  int r0 = tid >> 2, g0 = (tid & 3) * 8;

  for (int k0 = 0; k0 < K; k0 += BK) {
    gload16(Ab + (long)r0 * K + k0 + g0,        &As[(size_t)tid * 8]);
    gload16(Ab + (long)(r0 + 64) * K + k0 + g0, &As[(size_t)(256 + tid) * 8]);
    gload16(Bb + (long)r0 * K + k0 + g0,        &Bs[(size_t)tid * 8]);
    gload16(Bb + (long)(r0 + 64) * K + k0 + g0, &Bs[(size_t)(256 + tid) * 8]);
    __syncthreads();
    bf16x8 af[4], bf[4];
#pragma unroll
    for (int i = 0; i < 4; i++)
      af[i] = *(const bf16x8*)&As[(wr + i * 16 + (lane & 15)) * BK + (lane >> 4) * 8];
#pragma unroll
    for (int j = 0; j < 4; j++)
      bf[j] = *(const bf16x8*)&Bs[(wc + j * 16 + (lane & 15)) * BK + (lane >> 4) * 8];
#pragma unroll
    for (int i = 0; i < 4; i++)
#pragma unroll
      for (int j = 0; j < 4; j++)
        acc[i][j] = __builtin_amdgcn_mfma_f32_16x16x32_bf16(af[i], bf[j], acc[i][j], 0, 0, 0);
    __syncthreads();
  }

#pragma unroll
  for (int j = 0; j < 4; j++) {
    int col = n0 + wc + j * 16 + (lane & 15);
    float bv = bias[col];
#pragma unroll
    for (int i = 0; i < 4; i++) {
      int rbase = m0 + wr + i * 16 + ((lane >> 4) << 2);
      f32x4 v = acc[i][j];
#pragma unroll
      for (int r = 0; r < 4; r++)
        C[(long)(rbase + r) * N + col] = f2b(v[r] + bv);
    }
  }
}

// ---------- persistent GRU recurrence, one layer ----------
// 64 wgs x 256 thr (cooperative). wg g owns output cols [16g,16g+16) for all 3 gates.
// Whh resident: gates r,z in LDS (64 KB), gate n in 128 VGPRs/wave.
// h(t-1) A-fragments loaded direct global->VGPR each step (batched, 1 latency exposure).
__global__ __launch_bounds__(256, 1) void gru_recur(
    const unsigned short* __restrict__ gi,    // [T*B][3072] bf16 (includes b_ih)
    const unsigned short* __restrict__ wsw,   // swizzled whh: [ntile192][kc32][64][8]
    const float* __restrict__ bhh,            // [3072]
    const float* __restrict__ h0,             // [64][1024] fp32
    unsigned short* __restrict__ hbuf,        // [2][64][1024] bf16 (double buffer)
    unsigned short* __restrict__ outseq,      // [T*B][1024] bf16 (layer output)
    float* __restrict__ hout)                 // [64][1024] fp32 -> d_out slice
{
  cg::grid_group grid = cg::this_grid();
  // B fragments for gates r,z: [p = gate*32+kc][lane][8]  = 64 KB
  __shared__ alignas(16) unsigned short Bs[64 * 64 * 8];
  int tid = threadIdx.x, wave = tid >> 6, lane = tid & 63;
  int g = blockIdx.x;
  int colc = g * 16 + (lane & 15);               // this lane's H-column
  int rowb = wave * 16 + ((lane >> 4) << 2);     // base batch row for 4 acc regs

  // ---- preload B gates r,z into LDS (16 wave-issues per wave) ----
#pragma unroll
  for (int i = 0; i < 16; i++) {
    int p = wave * 16 + i;                       // 0..63 = gate*32+kc
    int gate = p >> 5, kc = p & 31;
    const unsigned short* src =
        wsw + ((((long)gate * 64 + g) * 32 + kc) * 64 + lane) * 8;
    gload16(src, &Bs[(size_t)p * 512 + (size_t)lane * 8]);
  }
  // ---- preload B gate n into registers (32 frags = 128 VGPRs) ----
  bf16x8 bn[32];
#pragma unroll
  for (int kc = 0; kc < 32; kc++)
    bn[kc] = *(const bf16x8*)(wsw + ((((long)2 * 64 + g) * 32 + kc) * 64 + lane) * 8);

  // init fp32 h state in registers; publish bf16 h to buffer 0
  float h[4];
#pragma unroll
  for (int r = 0; r < 4; r++) {
    h[r] = h0[(rowb + r) * HDIM + colc];
    hbuf[(rowb + r) * HDIM + colc] = f2b(h[r]);
  }
  float bh_r = bhh[0 * HDIM + colc];
  float bh_z = bhh[1 * HDIM + colc];
  float bh_n = bhh[2 * HDIM + colc];
  __syncthreads();     // Bs ready (drains global_load_lds)
  grid.sync();

  int cur = 0;
#pragma unroll 1
  for (int t = 0; t < T_STEPS; t++) {
    // ---- prefetch gi_t (independent of h) ----
    const unsigned short* gib = gi + (long)t * BATCH * NGATE;
    unsigned short giv[3][4];
#pragma unroll
    for (int r = 0; r < 4; r++) {
      long grow = (long)(rowb + r) * NGATE;
#pragma unroll
      for (int gate = 0; gate < 3; gate++)
        giv[gate][r] = gib[grow + gate * HDIM + colc];
    }

    // ---- load all 32 A-fragments of h(t-1) for this wave's rowtile ----
    const unsigned short* hb = hbuf + (size_t)cur * (BATCH * HDIM);
    const unsigned short* ha = hb + (size_t)(wave * 16 + (lane & 15)) * HDIM
                                  + (size_t)(lane >> 4) * 8;
    bf16x8 af[32];
#pragma unroll
    for (int kc = 0; kc < 32; kc++)
      af[kc] = *(const bf16x8*)(ha + kc * 32);

    // ---- MFMA: 3 gates x 32 kc ----
    f32x4 acc[3] = {};
#pragma unroll
    for (int kc = 0; kc < 32; kc++) {
      bf16x8 b_r = *(const bf16x8*)&Bs[(size_t)(0 * 32 + kc) * 512 + (size_t)lane * 8];
      bf16x8 b_z = *(const bf16x8*)&Bs[(size_t)(1 * 32 + kc) * 512 + (size_t)lane * 8];
      acc[0] = __builtin_amdgcn_mfma_f32_16x16x32_bf16(af[kc], b_r, acc[0], 0, 0, 0);
      acc[1] = __builtin_amdgcn_mfma_f32_16x16x32_bf16(af[kc], b_z, acc[1], 0, 0, 0);
      acc[2] = __builtin_amdgcn_mfma_f32_16x16x32_bf16(af[kc], bn[kc], acc[2], 0, 0, 0);
    }

    // ---- gates + state update (C/D: col=lane&15, row=(lane>>4)*4+reg) ----
    unsigned short* ob = outseq + (long)t * BATCH * HDIM;
    unsigned short* hn = hbuf + (size_t)(cur ^ 1) * (BATCH * HDIM);
#pragma unroll
    for (int r = 0; r < 4; r++) {
      float gr = b2f(giv[0][r]);
      float gz = b2f(giv[1][r]);
      float gn = b2f(giv[2][r]);
      float xr = gr + acc[0][r] + bh_r;
      float xz = gz + acc[1][r] + bh_z;
      float rr = 1.0f / (1.0f + __expf(-xr));
      float zz = 1.0f / (1.0f + __expf(-xz));
      float xn = gn + rr * (acc[2][r] + bh_n);
      float e2 = __expf(-2.0f * xn);
      float nn = (1.0f - e2) / (1.0f + e2);      // tanh
      float hv = (1.0f - zz) * nn + zz * h[r];
      h[r] = hv;
      unsigned short hb16 = f2b(hv);
      ob[(rowb + r) * HDIM + colc] = hb16;
      hn[(rowb + r) * HDIM + colc] = hb16;
      if (t == T_STEPS - 1) hout[(rowb + r) * HDIM + colc] = hv;
    }
    cur ^= 1;
    grid.sync();
  }
}

// ---------- host ----------
extern "C" void kernel_launch(void* const* d_in, const int* in_sizes, int n_in,
                              void* d_out, int out_size, void* d_ws, size_t ws_size,
                              hipStream_t stream) {
  const float* x   = (const float*)d_in[0];
  const float* h0  = (const float*)d_in[1];
  const float* wih = (const float*)d_in[2];
  const float* whh = (const float*)d_in[3];
  const float* bih = (const float*)d_in[4];
  const float* bhh = (const float*)d_in[5];
  float* out = (float*)d_out;

  char* ws = (char*)d_ws;
  unsigned short* xb   = (unsigned short*)ws; ws += (size_t)16384 * 1024 * 2;
  unsigned short* yb   = (unsigned short*)ws; ws += (size_t)16384 * 1024 * 2;
  unsigned short* gib  = (unsigned short*)ws; ws += (size_t)16384 * 3072 * 2;
  unsigned short* wihb = (unsigned short*)ws; ws += (size_t)3 * 3072 * 1024 * 2;
  unsigned short* wsw  = (unsigned short*)ws; ws += (size_t)3 * 3072 * 1024 * 2;
  unsigned short* hbuf = (unsigned short*)ws; ws += (size_t)2 * 64 * 1024 * 2;

  f2b_kernel<<<16384, 256, 0, stream>>>(x,   xb,   16777216 / 4);
  f2b_kernel<<<dim3((9437184 / 4 + 255) / 256), 256, 0, stream>>>(wih, wihb, 9437184 / 4);
  swizzle_whh<<<4608, 256, 0, stream>>>(whh, wsw);

  unsigned short* seq_in = xb;
  unsigned short* seq_out = yb;
  for (int l = 0; l < LAYERS; l++) {
    gemm_gi<<<dim3(16384 / BM, 3072 / BN), 256, 0, stream>>>(
        seq_in, wihb + (size_t)l * NGATE * KDIM, bih + l * NGATE, gib,
        16384, NGATE, KDIM);

    const unsigned short* a_gi  = gib;
    const unsigned short* a_wsw = wsw + (size_t)l * NGATE * KDIM;
    const float* a_bhh = bhh + l * NGATE;
    const float* a_h0  = h0 + (size_t)l * BATCH * HDIM;
    unsigned short* a_hbuf = hbuf;
    unsigned short* a_out  = seq_out;
    float* a_hout = out + (size_t)l * BATCH * HDIM;
    void* args[] = {&a_gi, &a_wsw, &a_bhh, &a_h0, &a_hbuf, &a_out, &a_hout};
    hipLaunchCooperativeKernel((void*)gru_recur, dim3(64), dim3(256), args, 0, stream);

    unsigned short* tmp = seq_in; seq_in = seq_out; seq_out = tmp;
  }
}

// Round 4
// 6678.181 us; speedup vs baseline: 2.3168x; 1.7896x over previous
//
#include <hip/hip_runtime.h>
#include <hip/hip_bf16.h>
#include <hip/hip_cooperative_groups.h>

namespace cg = cooperative_groups;

typedef __attribute__((ext_vector_type(8))) short bf16x8;
typedef __attribute__((ext_vector_type(4))) float f32x4;

#define T_STEPS 256
#define BATCH   64
#define KDIM    1024
#define HDIM    1024
#define NGATE   3072   // 3*HDIM
#define LAYERS  3
#define NWG     64
#define SLOTE   (BATCH * HDIM)   // elements per h ring slot

// ---------- helpers ----------
__device__ __forceinline__ unsigned short f2b(float f) {
  union { float f; unsigned int u; } a; a.f = f;
  unsigned int u = a.u;
  unsigned int r = (u + 0x7FFFu + ((u >> 16) & 1u)) >> 16;  // RNE
  return (unsigned short)r;
}
__device__ __forceinline__ float b2f(unsigned short h) {
  union { unsigned int u; float f; } a; a.u = ((unsigned int)h) << 16;
  return a.f;
}
__device__ __forceinline__ void gload16(const void* gptr, void* ldsptr) {
  __builtin_amdgcn_global_load_lds(
      (const __attribute__((address_space(1))) unsigned int*)gptr,
      (__attribute__((address_space(3))) unsigned int*)ldsptr,
      16, 0, 0);
}

// ---------- fp32 -> bf16 bulk convert (4 elems/thread) ----------
__global__ void f2b_kernel(const float* __restrict__ src,
                           unsigned short* __restrict__ dst, int n4) {
  int i = blockIdx.x * blockDim.x + threadIdx.x;
  if (i < n4) {
    float4 v = ((const float4*)src)[i];
    ushort4 o;
    o.x = f2b(v.x); o.y = f2b(v.y); o.z = f2b(v.z); o.w = f2b(v.w);
    ((ushort4*)dst)[i] = o;
  }
}

// ---------- swizzle whh into MFMA B-fragment-major layout ----------
// out layout: [l][ntile(192)][kc(32)][lane(64)][8 bf16]
__global__ void swizzle_whh(const float* __restrict__ whh,
                            unsigned short* __restrict__ out) {
  long gid = (long)blockIdx.x * 256 + threadIdx.x;   // < 3*192*32*64
  int lane = (int)(gid & 63);
  long rest = gid >> 6;
  int kc = (int)(rest & 31); rest >>= 5;
  int ntile = (int)(rest % 192); int l = (int)(rest / 192);
  int n  = ntile * 16 + (lane & 15);
  int k0 = kc * 32 + (lane >> 4) * 8;
  const float* src = whh + (((long)l * NGATE + n) * KDIM + k0);
  unsigned short o[8];
#pragma unroll
  for (int j = 0; j < 8; j++) o[j] = f2b(src[j]);
  bf16x8 v = *(bf16x8*)o;
  *(bf16x8*)(out + gid * 8) = v;
}

// ---------- gi GEMM: C[M,N] = A[M,K] * B[N,K]^T + bias ----------
#define BM 128
#define BN 128
#define BK 32
__global__ __launch_bounds__(256) void gemm_gi(
    const unsigned short* __restrict__ A,   // [M][K] bf16
    const unsigned short* __restrict__ B,   // [N][K] bf16
    const float* __restrict__ bias,         // [N]
    unsigned short* __restrict__ C,         // [M][N] bf16
    int M, int N, int K) {
  __shared__ alignas(16) unsigned short As[BM * BK];
  __shared__ alignas(16) unsigned short Bs[BN * BK];
  int tid = threadIdx.x;
  int wave = tid >> 6, lane = tid & 63;
  int m0 = blockIdx.x * BM, n0 = blockIdx.y * BN;
  int wr = (wave >> 1) * 64, wc = (wave & 1) * 64;

  f32x4 acc[4][4] = {};

  const unsigned short* Ab = A + (long)m0 * K;
  const unsigned short* Bb = B + (long)n0 * K;
  int r0 = tid >> 2, g0 = (tid & 3) * 8;

  for (int k0 = 0; k0 < K; k0 += BK) {
    gload16(Ab + (long)r0 * K + k0 + g0,        &As[(size_t)tid * 8]);
    gload16(Ab + (long)(r0 + 64) * K + k0 + g0, &As[(size_t)(256 + tid) * 8]);
    gload16(Bb + (long)r0 * K + k0 + g0,        &Bs[(size_t)tid * 8]);
    gload16(Bb + (long)(r0 + 64) * K + k0 + g0, &Bs[(size_t)(256 + tid) * 8]);
    __syncthreads();
    bf16x8 af[4], bf[4];
#pragma unroll
    for (int i = 0; i < 4; i++)
      af[i] = *(const bf16x8*)&As[(wr + i * 16 + (lane & 15)) * BK + (lane >> 4) * 8];
#pragma unroll
    for (int j = 0; j < 4; j++)
      bf[j] = *(const bf16x8*)&Bs[(wc + j * 16 + (lane & 15)) * BK + (lane >> 4) * 8];
#pragma unroll
    for (int i = 0; i < 4; i++)
#pragma unroll
      for (int j = 0; j < 4; j++)
        acc[i][j] = __builtin_amdgcn_mfma_f32_16x16x32_bf16(af[i], bf[j], acc[i][j], 0, 0, 0);
    __syncthreads();
  }

#pragma unroll
  for (int j = 0; j < 4; j++) {
    int col = n0 + wc + j * 16 + (lane & 15);
    float bv = bias[col];
#pragma unroll
    for (int i = 0; i < 4; i++) {
      int rbase = m0 + wr + i * 16 + ((lane >> 4) << 2);
      f32x4 v = acc[i][j];
#pragma unroll
      for (int r = 0; r < 4; r++)
        C[(long)(rbase + r) * N + col] = f2b(v[r] + bv);
    }
  }
}

// ---------- GRU recurrence, ring-buffer variant (primary) ----------
// Plain launch, 64 wgs x 256 thr. wg g owns output cols [16g,16g+16) for all 3 gates.
// h exchanged via 257-slot ring: step t reads slot (T-t), writes slot (T-t-1).
// Every read address is first-touch within the dispatch -> local L2 miss -> fresh
// from LLC (writes are agent-scope write-through). Ring reversed so streaming
// prefetch crosses into already-consumed slots only. No cache-maintenance ops.
__global__ __launch_bounds__(256, 1) void gru_recur_ring(
    const unsigned short* __restrict__ gi,    // [T*B][3072] bf16 (includes b_ih)
    const unsigned short* __restrict__ wsw,   // swizzled whh: [ntile192][kc32][64][8]
    const float* __restrict__ bhh,            // [3072]
    const float* __restrict__ h0,             // [64][1024] fp32
    unsigned short* __restrict__ ring,        // [257][64][1024] bf16
    unsigned short* __restrict__ outseq,      // [T*B][1024] bf16 (layer output)
    float* __restrict__ hout,                 // [64][1024] fp32 -> d_out slice
    unsigned int* __restrict__ bar,           // monotonic barrier counter
    unsigned int bar_base)                    // barrier slots consumed by prior layers
{
  __shared__ alignas(16) unsigned short Bs[64 * 64 * 8];   // gates r,z B-frags, 64 KB
  int tid = threadIdx.x, wave = tid >> 6, lane = tid & 63;
  int g = blockIdx.x;
  int colc = g * 16 + (lane & 15);
  int rowb = wave * 16 + ((lane >> 4) << 2);

  // ---- preload B gates r,z into LDS ----
#pragma unroll
  for (int i = 0; i < 16; i++) {
    int p = wave * 16 + i;                       // 0..63 = gate*32+kc
    int gate = p >> 5, kc = p & 31;
    const unsigned short* src =
        wsw + ((((long)gate * 64 + g) * 32 + kc) * 64 + lane) * 8;
    gload16(src, &Bs[(size_t)p * 512 + (size_t)lane * 8]);
  }
  // ---- preload B gate n into registers ----
  bf16x8 bn[32];
#pragma unroll
  for (int kc = 0; kc < 32; kc++)
    bn[kc] = *(const bf16x8*)(wsw + ((((long)2 * 64 + g) * 32 + kc) * 64 + lane) * 8);

  // ---- init fp32 h in registers; publish bf16 h0 to ring slot 0 (agent scope) ----
  float h[4];
  unsigned short* slot0 = ring + (size_t)T_STEPS * SLOTE;
#pragma unroll
  for (int r = 0; r < 4; r++) {
    h[r] = h0[(rowb + r) * HDIM + colc];
    __hip_atomic_store(slot0 + (rowb + r) * HDIM + colc, f2b(h[r]),
                       __ATOMIC_RELAXED, __HIP_MEMORY_SCOPE_AGENT);
  }
  float bh_r = bhh[0 * HDIM + colc];
  float bh_z = bhh[1 * HDIM + colc];
  float bh_n = bhh[2 * HDIM + colc];

  __syncthreads();   // drains vmcnt: Bs staged + h0 at LLC

  unsigned int bidx = bar_base;
  if (tid == 0)
    __hip_atomic_fetch_add(bar, 1u, __ATOMIC_RELAXED, __HIP_MEMORY_SCOPE_AGENT);
  // prefetch gi(0) while waiting
  unsigned short giv[3][4];
  {
    const unsigned short* gib = gi;
#pragma unroll
    for (int r = 0; r < 4; r++) {
      long grow = (long)(rowb + r) * NGATE;
#pragma unroll
      for (int gate = 0; gate < 3; gate++)
        giv[gate][r] = gib[grow + gate * HDIM + colc];
    }
  }
  if (tid == 0) {
    while (__hip_atomic_load(bar, __ATOMIC_RELAXED, __HIP_MEMORY_SCOPE_AGENT)
           < (bidx + 1) * NWG) {}
  }
  bidx++;
  __syncthreads();

#pragma unroll 1
  for (int t = 0; t < T_STEPS; t++) {
    // ---- read h(t-1) from ring slot (T-t): first touch, plain vector loads ----
    const unsigned short* hb = ring + (size_t)(T_STEPS - t) * SLOTE;
    const unsigned short* ha = hb + (size_t)(wave * 16 + (lane & 15)) * HDIM
                                  + (size_t)(lane >> 4) * 8;
    bf16x8 af[32];
#pragma unroll
    for (int kc = 0; kc < 32; kc++)
      af[kc] = *(const bf16x8*)(ha + kc * 32);

    // ---- MFMA: 3 gates x 32 kc ----
    f32x4 acc[3] = {};
#pragma unroll
    for (int kc = 0; kc < 32; kc++) {
      bf16x8 b_r = *(const bf16x8*)&Bs[(size_t)(0 * 32 + kc) * 512 + (size_t)lane * 8];
      bf16x8 b_z = *(const bf16x8*)&Bs[(size_t)(1 * 32 + kc) * 512 + (size_t)lane * 8];
      acc[0] = __builtin_amdgcn_mfma_f32_16x16x32_bf16(af[kc], b_r, acc[0], 0, 0, 0);
      acc[1] = __builtin_amdgcn_mfma_f32_16x16x32_bf16(af[kc], b_z, acc[1], 0, 0, 0);
      acc[2] = __builtin_amdgcn_mfma_f32_16x16x32_bf16(af[kc], bn[kc], acc[2], 0, 0, 0);
    }

    // ---- gates + state update (C/D: col=lane&15, row=(lane>>4)*4+reg) ----
    unsigned short* ob = outseq + (long)t * BATCH * HDIM;
    unsigned short* hn = ring + (size_t)(T_STEPS - 1 - t) * SLOTE;   // slot t+1
#pragma unroll
    for (int r = 0; r < 4; r++) {
      float gr = b2f(giv[0][r]);
      float gz = b2f(giv[1][r]);
      float gn = b2f(giv[2][r]);
      float xr = gr + acc[0][r] + bh_r;
      float xz = gz + acc[1][r] + bh_z;
      float rr = 1.0f / (1.0f + __expf(-xr));
      float zz = 1.0f / (1.0f + __expf(-xz));
      float xn = gn + rr * (acc[2][r] + bh_n);
      float e2 = __expf(-2.0f * xn);
      float nn = (1.0f - e2) / (1.0f + e2);      // tanh
      float hv = (1.0f - zz) * nn + zz * h[r];
      h[r] = hv;
      unsigned short hb16 = f2b(hv);
      ob[(rowb + r) * HDIM + colc] = hb16;                  // plain (next dispatch)
      __hip_atomic_store(hn + (rowb + r) * HDIM + colc, hb16,
                         __ATOMIC_RELAXED, __HIP_MEMORY_SCOPE_AGENT);
      if (t == T_STEPS - 1) hout[(rowb + r) * HDIM + colc] = hv;
    }

    // ---- barrier: syncthreads drains stores to LLC; arrive; prefetch; spin ----
    __syncthreads();
    if (tid == 0)
      __hip_atomic_fetch_add(bar, 1u, __ATOMIC_RELAXED, __HIP_MEMORY_SCOPE_AGENT);
    if (t + 1 < T_STEPS) {
      const unsigned short* gib = gi + (long)(t + 1) * BATCH * NGATE;
#pragma unroll
      for (int r = 0; r < 4; r++) {
        long grow = (long)(rowb + r) * NGATE;
#pragma unroll
        for (int gate = 0; gate < 3; gate++)
          giv[gate][r] = gib[grow + gate * HDIM + colc];
      }
      if (tid == 0) {
        while (__hip_atomic_load(bar, __ATOMIC_RELAXED, __HIP_MEMORY_SCOPE_AGENT)
               < (bidx + 1) * NWG) {}
      }
    }
    bidx++;
    __syncthreads();
  }
}

// ---------- GRU recurrence, cooperative fallback (byte-for-byte Round-2 logic) ----------
__global__ __launch_bounds__(256, 1) void gru_recur_cg(
    const unsigned short* __restrict__ gi,
    const unsigned short* __restrict__ wsw,
    const float* __restrict__ bhh,
    const float* __restrict__ h0,
    unsigned short* __restrict__ hbuf,        // [2][64][1024] bf16
    unsigned short* __restrict__ outseq,
    float* __restrict__ hout)
{
  cg::grid_group grid = cg::this_grid();
  __shared__ alignas(16) unsigned short Bs[64 * 64 * 8];
  int tid = threadIdx.x, wave = tid >> 6, lane = tid & 63;
  int g = blockIdx.x;
  int colc = g * 16 + (lane & 15);
  int rowb = wave * 16 + ((lane >> 4) << 2);

#pragma unroll
  for (int i = 0; i < 16; i++) {
    int p = wave * 16 + i;
    int gate = p >> 5, kc = p & 31;
    const unsigned short* src =
        wsw + ((((long)gate * 64 + g) * 32 + kc) * 64 + lane) * 8;
    gload16(src, &Bs[(size_t)p * 512 + (size_t)lane * 8]);
  }
  bf16x8 bn[32];
#pragma unroll
  for (int kc = 0; kc < 32; kc++)
    bn[kc] = *(const bf16x8*)(wsw + ((((long)2 * 64 + g) * 32 + kc) * 64 + lane) * 8);

  float h[4];
#pragma unroll
  for (int r = 0; r < 4; r++) {
    h[r] = h0[(rowb + r) * HDIM + colc];
    hbuf[(rowb + r) * HDIM + colc] = f2b(h[r]);
  }
  float bh_r = bhh[0 * HDIM + colc];
  float bh_z = bhh[1 * HDIM + colc];
  float bh_n = bhh[2 * HDIM + colc];
  __syncthreads();
  grid.sync();

  int cur = 0;
#pragma unroll 1
  for (int t = 0; t < T_STEPS; t++) {
    const unsigned short* gib = gi + (long)t * BATCH * NGATE;
    unsigned short giv[3][4];
#pragma unroll
    for (int r = 0; r < 4; r++) {
      long grow = (long)(rowb + r) * NGATE;
#pragma unroll
      for (int gate = 0; gate < 3; gate++)
        giv[gate][r] = gib[grow + gate * HDIM + colc];
    }

    const unsigned short* hb = hbuf + (size_t)cur * (BATCH * HDIM);
    const unsigned short* ha = hb + (size_t)(wave * 16 + (lane & 15)) * HDIM
                                  + (size_t)(lane >> 4) * 8;
    bf16x8 af[32];
#pragma unroll
    for (int kc = 0; kc < 32; kc++)
      af[kc] = *(const bf16x8*)(ha + kc * 32);

    f32x4 acc[3] = {};
#pragma unroll
    for (int kc = 0; kc < 32; kc++) {
      bf16x8 b_r = *(const bf16x8*)&Bs[(size_t)(0 * 32 + kc) * 512 + (size_t)lane * 8];
      bf16x8 b_z = *(const bf16x8*)&Bs[(size_t)(1 * 32 + kc) * 512 + (size_t)lane * 8];
      acc[0] = __builtin_amdgcn_mfma_f32_16x16x32_bf16(af[kc], b_r, acc[0], 0, 0, 0);
      acc[1] = __builtin_amdgcn_mfma_f32_16x16x32_bf16(af[kc], b_z, acc[1], 0, 0, 0);
      acc[2] = __builtin_amdgcn_mfma_f32_16x16x32_bf16(af[kc], bn[kc], acc[2], 0, 0, 0);
    }

    unsigned short* ob = outseq + (long)t * BATCH * HDIM;
    unsigned short* hn = hbuf + (size_t)(cur ^ 1) * (BATCH * HDIM);
#pragma unroll
    for (int r = 0; r < 4; r++) {
      float gr = b2f(giv[0][r]);
      float gz = b2f(giv[1][r]);
      float gn = b2f(giv[2][r]);
      float xr = gr + acc[0][r] + bh_r;
      float xz = gz + acc[1][r] + bh_z;
      float rr = 1.0f / (1.0f + __expf(-xr));
      float zz = 1.0f / (1.0f + __expf(-xz));
      float xn = gn + rr * (acc[2][r] + bh_n);
      float e2 = __expf(-2.0f * xn);
      float nn = (1.0f - e2) / (1.0f + e2);
      float hv = (1.0f - zz) * nn + zz * h[r];
      h[r] = hv;
      unsigned short hb16 = f2b(hv);
      ob[(rowb + r) * HDIM + colc] = hb16;
      hn[(rowb + r) * HDIM + colc] = hb16;
      if (t == T_STEPS - 1) hout[(rowb + r) * HDIM + colc] = hv;
    }
    cur ^= 1;
    grid.sync();
  }
}

// ---------- host ----------
extern "C" void kernel_launch(void* const* d_in, const int* in_sizes, int n_in,
                              void* d_out, int out_size, void* d_ws, size_t ws_size,
                              hipStream_t stream) {
  const float* x   = (const float*)d_in[0];
  const float* h0  = (const float*)d_in[1];
  const float* wih = (const float*)d_in[2];
  const float* whh = (const float*)d_in[3];
  const float* bih = (const float*)d_in[4];
  const float* bhh = (const float*)d_in[5];
  float* out = (float*)d_out;

  char* ws = (char*)d_ws;
  unsigned short* xb   = (unsigned short*)ws; ws += (size_t)16384 * 1024 * 2;
  unsigned short* yb   = (unsigned short*)ws; ws += (size_t)16384 * 1024 * 2;
  unsigned short* gib  = (unsigned short*)ws; ws += (size_t)16384 * 3072 * 2;
  unsigned short* wihb = (unsigned short*)ws; ws += (size_t)3 * 3072 * 1024 * 2;
  unsigned short* wsw  = (unsigned short*)ws; ws += (size_t)3 * 3072 * 1024 * 2;
  unsigned short* ring = (unsigned short*)ws; ws += (size_t)(T_STEPS + 1) * SLOTE * 2;
  unsigned int*   bar  = (unsigned int*)ws;   ws += 256;
  size_t need = (size_t)(ws - (char*)d_ws);
  bool use_ring = (ws_size >= need);
  unsigned short* hbuf = ring;   // fallback reuses first 256 KB of ring area

  hipMemsetAsync(bar, 0, 256, stream);
  f2b_kernel<<<16384, 256, 0, stream>>>(x,   xb,   16777216 / 4);
  f2b_kernel<<<dim3((9437184 / 4 + 255) / 256), 256, 0, stream>>>(wih, wihb, 9437184 / 4);
  swizzle_whh<<<4608, 256, 0, stream>>>(whh, wsw);

  unsigned short* seq_in = xb;
  unsigned short* seq_out = yb;
  for (int l = 0; l < LAYERS; l++) {
    gemm_gi<<<dim3(16384 / BM, 3072 / BN), 256, 0, stream>>>(
        seq_in, wihb + (size_t)l * NGATE * KDIM, bih + l * NGATE, gib,
        16384, NGATE, KDIM);

    const unsigned short* a_wsw = wsw + (size_t)l * NGATE * KDIM;
    const float* a_bhh = bhh + l * NGATE;
    const float* a_h0  = h0 + (size_t)l * BATCH * HDIM;
    float* a_hout = out + (size_t)l * BATCH * HDIM;

    if (use_ring) {
      gru_recur_ring<<<NWG, 256, 0, stream>>>(
          gib, a_wsw, a_bhh, a_h0, ring, seq_out, a_hout,
          bar, (unsigned int)l * (T_STEPS + 1));
    } else {
      const unsigned short* a_gi = gib;
      unsigned short* a_hbuf = hbuf;
      unsigned short* a_out  = seq_out;
      void* args[] = {&a_gi, &a_wsw, &a_bhh, &a_h0, &a_hbuf, &a_out, &a_hout};
      hipLaunchCooperativeKernel((void*)gru_recur_cg, dim3(NWG), dim3(256), args, 0, stream);
    }

    unsigned short* tmp = seq_in; seq_in = seq_out; seq_out = tmp;
  }
}